// Round 1
// baseline (541.438 us; speedup 1.0000x reference)
//
#include <hip/hip_runtime.h>
#include <stdint.h>

#define IN_F 4096
#define OUT_F 4096
#define M_ROWS 8192

__device__ __constant__ float c_nf4[16] = {
    -1.0f, -0.6961928f, -0.52507305f, -0.3949175f, -0.28444138f, -0.18477343f,
    -0.09105004f, 0.0f, 0.0795803f, 0.1609302f, 0.2461123f, 0.33791524f,
    0.44070983f, 0.562617f, 0.72295684f, 1.0f};

typedef __bf16 bf16x8 __attribute__((ext_vector_type(8)));
typedef float f32x4 __attribute__((ext_vector_type(4)));

__device__ __forceinline__ unsigned short f2bf(float f) {
  uint32_t u = __builtin_bit_cast(uint32_t, f);
  u += 0x7fffu + ((u >> 16) & 1u);  // round-to-nearest-even; data has no NaN/Inf
  return (unsigned short)(u >> 16);
}

// ---------------------------------------------------------------------------
// Dequantize NF4: packed int32 codes (1 byte each) -> bf16 W[OUT_F][IN_F],
// scale folded in. Each thread: 4 codes -> 8 bf16 (one 16B store).
// ---------------------------------------------------------------------------
__global__ __launch_bounds__(256) void k_dequant(
    const int* __restrict__ packed, const float* __restrict__ scale,
    unsigned short* __restrict__ W) {
  __shared__ float cb[16];
  if (threadIdx.x < 16) cb[threadIdx.x] = c_nf4[threadIdx.x];
  __syncthreads();
  const int tid = blockIdx.x * 256 + threadIdx.x;
  const int4 c4 = ((const int4*)packed)[tid];
  const float s = scale[tid >> 9];  // 8 outputs/thread, 4096/row -> row = tid/512
  const int cs[4] = {c4.x, c4.y, c4.z, c4.w};
  union { unsigned short h[8]; int4 v; } o;
#pragma unroll
  for (int i = 0; i < 4; ++i) {
    o.h[2 * i]     = f2bf(cb[cs[i] & 15] * s);
    o.h[2 * i + 1] = f2bf(cb[(cs[i] >> 4) & 15] * s);
  }
  ((int4*)W)[tid] = o.v;
}

// ---------------------------------------------------------------------------
// Convert x fp32 -> bf16. Each thread: 8 floats (2x float4 load, 1x 16B store)
// ---------------------------------------------------------------------------
__global__ __launch_bounds__(256) void k_cvt(const float* __restrict__ x,
                                             unsigned short* __restrict__ xb) {
  const int tid = blockIdx.x * 256 + threadIdx.x;
  const float4* x4 = (const float4*)x;
  const float4 a = x4[2 * tid];
  const float4 b = x4[2 * tid + 1];
  union { unsigned short h[8]; int4 v; } o;
  o.h[0] = f2bf(a.x); o.h[1] = f2bf(a.y); o.h[2] = f2bf(a.z); o.h[3] = f2bf(a.w);
  o.h[4] = f2bf(b.x); o.h[5] = f2bf(b.y); o.h[6] = f2bf(b.z); o.h[7] = f2bf(b.w);
  ((int4*)xb)[tid] = o.v;
}

// ---------------------------------------------------------------------------
// bf16 GEMM, NT layout: C[M][N] = A[M][K] * B[N][K]^T + bias
// 128x128 block tile, BK=32, 4 waves in 2x2 (64x64 each), 16x16x32 MFMA.
// global_load_lds width=16 staging (wave-uniform LDS base + lane*16).
// ---------------------------------------------------------------------------
#define GLL(gptr, lptr)                                          \
  __builtin_amdgcn_global_load_lds(                              \
      (__attribute__((address_space(1))) void*)(gptr),           \
      (__attribute__((address_space(3))) void*)(lptr), 16, 0, 0)

__global__ __launch_bounds__(256) void k_gemm(
    const unsigned short* __restrict__ A,   // bf16 [M_ROWS][IN_F]
    const unsigned short* __restrict__ B,   // bf16 [OUT_F][IN_F]
    const float* __restrict__ bias,
    float* __restrict__ C) {                // fp32 [M_ROWS][OUT_F]
  __shared__ __align__(16) unsigned short sA[128 * 32];
  __shared__ __align__(16) unsigned short sB[128 * 32];
  const int tid = threadIdx.x;
  const int lane = tid & 63;
  const int w  = tid >> 6;   // wave 0..3
  const int wm = w >> 1;     // 2x2 wave grid
  const int wn = w & 1;
  const int bm = blockIdx.y * 128;
  const int bn = blockIdx.x * 128;

  f32x4 acc[4][4] = {};

  // Staging: wave w loads rows [w*32, w*32+32) of each tile.
  // Lane l covers (row = l>>2, col = (l&3)*8) of a 16-row chunk; LDS dest is
  // wave-uniform base + lane*16 -> row-major [128][32] unpadded.
  const unsigned short* gA =
      A + (size_t)(bm + w * 32 + (lane >> 2)) * IN_F + (lane & 3) * 8;
  const unsigned short* gB =
      B + (size_t)(bn + w * 32 + (lane >> 2)) * IN_F + (lane & 3) * 8;
  unsigned short* lA = sA + w * 32 * 32;  // wave-uniform
  unsigned short* lB = sB + w * 32 * 32;

  const int fr = lane & 15;        // m/n within 16-tile
  const int fk = (lane >> 4) * 8;  // k offset within BK=32

  for (int k0 = 0; k0 < IN_F; k0 += 32) {
    GLL(gA + k0, lA);
    GLL(gA + k0 + 16 * IN_F, lA + 16 * 32);
    GLL(gB + k0, lB);
    GLL(gB + k0 + 16 * IN_F, lB + 16 * 32);
    __syncthreads();  // compiler emits vmcnt(0) drain before s_barrier

    bf16x8 af[4], bfv[4];
#pragma unroll
    for (int t = 0; t < 4; ++t) {
      af[t]  = *(const bf16x8*)&sA[(wm * 64 + t * 16 + fr) * 32 + fk];
      bfv[t] = *(const bf16x8*)&sB[(wn * 64 + t * 16 + fr) * 32 + fk];
    }
#pragma unroll
    for (int i = 0; i < 4; ++i)
#pragma unroll
      for (int j = 0; j < 4; ++j)
        acc[i][j] = __builtin_amdgcn_mfma_f32_16x16x32_bf16(af[i], bfv[j],
                                                            acc[i][j], 0, 0, 0);
    __syncthreads();
  }

  // Epilogue: D mapping col = lane&15 (n), row = (lane>>4)*4 + reg (m)
  const int col0 = bn + wn * 64 + fr;
  const int row0 = bm + wm * 64 + (lane >> 4) * 4;
#pragma unroll
  for (int j = 0; j < 4; ++j) {
    const int col = col0 + j * 16;
    const float bv = bias[col];
#pragma unroll
    for (int i = 0; i < 4; ++i) {
      const int row = row0 + i * 16;
#pragma unroll
      for (int r = 0; r < 4; ++r)
        C[(size_t)(row + r) * OUT_F + col] = acc[i][j][r] + bv;
    }
  }
}

extern "C" void kernel_launch(void* const* d_in, const int* in_sizes, int n_in,
                              void* d_out, int out_size, void* d_ws, size_t ws_size,
                              hipStream_t stream) {
  const float* x      = (const float*)d_in[0];   // [4,2048,4096] fp32
  const int* packed   = (const int*)d_in[1];     // [OUT_F*IN_F/2] int32
  const float* scale  = (const float*)d_in[2];   // [OUT_F,1] fp32
  const float* bias   = (const float*)d_in[3];   // [OUT_F] fp32
  float* out = (float*)d_out;                    // [4,2048,4096] fp32

  unsigned short* Wb = (unsigned short*)d_ws;                  // 33.5 MB bf16 W
  unsigned short* Xb = (unsigned short*)((char*)d_ws + (size_t)OUT_F * IN_F * 2);

  k_dequant<<<(OUT_F * IN_F / 2) / (256 * 4), 256, 0, stream>>>(packed, scale, Wb);
  k_cvt<<<(M_ROWS * IN_F) / (256 * 8), 256, 0, stream>>>(x, Xb);
  dim3 grid(OUT_F / 128, M_ROWS / 128);
  k_gemm<<<grid, 256, 0, stream>>>(Xb, Wb, bias, out);
}

// Round 2
// 415.294 us; speedup vs baseline: 1.3037x; 1.3037x over previous
//
#include <hip/hip_runtime.h>
#include <stdint.h>

#define IN_F 4096
#define OUT_F 4096
#define M_ROWS 8192

// NF4 codebook pre-scaled to int8: round(c * 127)
__device__ __constant__ int c_nf4_i8[16] = {
    -127, -88, -67, -50, -36, -23, -12, 0, 10, 20, 31, 43, 56, 71, 92, 127};

typedef int i32x4 __attribute__((ext_vector_type(4)));

// ---------------------------------------------------------------------------
// Quantize x per row: one block per row (4096 fp32). Each thread handles 16
// floats (4x float4, coalesced), block-reduces absmax, writes int8 + step.
// ---------------------------------------------------------------------------
__global__ __launch_bounds__(256) void k_quant_x(
    const float* __restrict__ x, signed char* __restrict__ xq,
    float* __restrict__ steps) {
  const int row = blockIdx.x;
  const int tid = threadIdx.x;
  const float4* xr = (const float4*)(x + (size_t)row * IN_F);
  float4 v[4];
  float m = 0.0f;
#pragma unroll
  for (int i = 0; i < 4; ++i) {
    v[i] = xr[tid + 256 * i];
    m = fmaxf(m, fmaxf(fmaxf(fabsf(v[i].x), fabsf(v[i].y)),
                       fmaxf(fabsf(v[i].z), fabsf(v[i].w))));
  }
#pragma unroll
  for (int off = 32; off > 0; off >>= 1) m = fmaxf(m, __shfl_xor(m, off));
  __shared__ float wmax[4];
  if ((tid & 63) == 0) wmax[tid >> 6] = m;
  __syncthreads();
  m = fmaxf(fmaxf(wmax[0], wmax[1]), fmaxf(wmax[2], wmax[3]));
  const float inv = (m > 0.0f) ? 127.0f / m : 0.0f;
  if (tid == 0) steps[row] = m * (1.0f / 127.0f);
  int* oq = (int*)(xq + (size_t)row * IN_F);
#pragma unroll
  for (int i = 0; i < 4; ++i) {
    int q0 = (int)rintf(v[i].x * inv);
    int q1 = (int)rintf(v[i].y * inv);
    int q2 = (int)rintf(v[i].z * inv);
    int q3 = (int)rintf(v[i].w * inv);
    oq[tid + 256 * i] =
        (q0 & 255) | ((q1 & 255) << 8) | ((q2 & 255) << 16) | (q3 << 24);
  }
}

// ---------------------------------------------------------------------------
// Dequantize NF4 -> int8 codebook values (scale folded into GEMM epilogue).
// 256-entry byte LUT: code -> (int8 lo | int8 hi << 8). Each thread: 8 codes
// (2x int4 load) -> 16 int8 (1x int4 store).
// ---------------------------------------------------------------------------
__global__ __launch_bounds__(256) void k_dequant(
    const int* __restrict__ packed, signed char* __restrict__ W) {
  __shared__ short lut[256];
  {
    const int b = threadIdx.x;
    const int lo = c_nf4_i8[b & 15], hi = c_nf4_i8[b >> 4];
    lut[b] = (short)((lo & 0xFF) | ((hi & 0xFF) << 8));
  }
  __syncthreads();
  const int tid = blockIdx.x * 256 + threadIdx.x;
  const int4 ca = ((const int4*)packed)[2 * tid];
  const int4 cb = ((const int4*)packed)[2 * tid + 1];
  union { short h[8]; int4 v; } o;
  o.h[0] = lut[ca.x]; o.h[1] = lut[ca.y]; o.h[2] = lut[ca.z]; o.h[3] = lut[ca.w];
  o.h[4] = lut[cb.x]; o.h[5] = lut[cb.y]; o.h[6] = lut[cb.z]; o.h[7] = lut[cb.w];
  ((int4*)W)[tid] = o.v;
}

// ---------------------------------------------------------------------------
// int8 GEMM, NT: C[M][N] = A[M][K] * B[N][K]^T, int32 acc, fp32 epilogue.
// 128x128 block tile, BK=64 (int8 -> 64B/row, same LDS/iter profile as the
// bf16 BK=32 version but half the iterations). mfma_i32_16x16x64_i8.
// ---------------------------------------------------------------------------
#define GLL(gptr, lptr)                                          \
  __builtin_amdgcn_global_load_lds(                              \
      (__attribute__((address_space(1))) void*)(gptr),           \
      (__attribute__((address_space(3))) void*)(lptr), 16, 0, 0)

__global__ __launch_bounds__(256) void k_gemm(
    const signed char* __restrict__ A,   // [M_ROWS][IN_F] int8
    const signed char* __restrict__ B,   // [OUT_F][IN_F] int8
    const float* __restrict__ steps,     // [M_ROWS] per-row x step
    const float* __restrict__ scale,     // [OUT_F] per-channel w scale
    const float* __restrict__ bias,      // [OUT_F]
    float* __restrict__ C) {             // [M_ROWS][OUT_F] fp32
  __shared__ __align__(16) signed char sA[128 * 64];
  __shared__ __align__(16) signed char sB[128 * 64];
  const int tid = threadIdx.x;
  const int lane = tid & 63;
  const int w  = tid >> 6;   // wave 0..3
  const int wm = w >> 1;     // 2x2 wave grid, 64x64 per wave
  const int wn = w & 1;
  const int bm = blockIdx.y * 128;
  const int bn = blockIdx.x * 128;

  i32x4 acc[4][4] = {};

  // Staging: wave w loads rows [w*32, w*32+32). Lane l: row = l>>2,
  // byte col = (l&3)*16. LDS dest wave-uniform base + lane*16 -> [128][64] u8.
  const signed char* gA =
      A + (size_t)(bm + w * 32 + (lane >> 2)) * IN_F + (lane & 3) * 16;
  const signed char* gB =
      B + (size_t)(bn + w * 32 + (lane >> 2)) * IN_F + (lane & 3) * 16;
  signed char* lA = sA + w * 32 * 64;
  signed char* lB = sB + w * 32 * 64;

  const int fr = lane & 15;         // m/n within 16-tile
  const int fk = (lane >> 4) * 16;  // k byte offset within BK=64

  for (int k0 = 0; k0 < IN_F; k0 += 64) {
    GLL(gA + k0, lA);
    GLL(gA + k0 + 16 * IN_F, lA + 16 * 64);
    GLL(gB + k0, lB);
    GLL(gB + k0 + 16 * IN_F, lB + 16 * 64);
    __syncthreads();

    i32x4 af[4], bf[4];
#pragma unroll
    for (int t = 0; t < 4; ++t) {
      af[t] = *(const i32x4*)&sA[(wm * 64 + t * 16 + fr) * 64 + fk];
      bf[t] = *(const i32x4*)&sB[(wn * 64 + t * 16 + fr) * 64 + fk];
    }
#pragma unroll
    for (int i = 0; i < 4; ++i)
#pragma unroll
      for (int j = 0; j < 4; ++j)
        acc[i][j] = __builtin_amdgcn_mfma_i32_16x16x64_i8(af[i], bf[j],
                                                          acc[i][j], 0, 0, 0);
    __syncthreads();
  }

  // Epilogue: D mapping col = lane&15 (n), row = (lane>>4)*4 + reg (m).
  // out = acc * steps[row] * scale[col]/127 + bias[col]
  const int col0 = bn + wn * 64 + fr;
  const int row0 = bm + wm * 64 + (lane >> 4) * 4;
  float srow[4][4];
#pragma unroll
  for (int i = 0; i < 4; ++i)
#pragma unroll
    for (int r = 0; r < 4; ++r) srow[i][r] = steps[row0 + i * 16 + r];
#pragma unroll
  for (int j = 0; j < 4; ++j) {
    const int col = col0 + j * 16;
    const float fc = scale[col] * (1.0f / 127.0f);
    const float bv = bias[col];
#pragma unroll
    for (int i = 0; i < 4; ++i) {
      const int row = row0 + i * 16;
#pragma unroll
      for (int r = 0; r < 4; ++r)
        C[(size_t)(row + r) * OUT_F + col] =
            (float)acc[i][j][r] * (srow[i][r] * fc) + bv;
    }
  }
}

extern "C" void kernel_launch(void* const* d_in, const int* in_sizes, int n_in,
                              void* d_out, int out_size, void* d_ws, size_t ws_size,
                              hipStream_t stream) {
  const float* x      = (const float*)d_in[0];   // [4,2048,4096] fp32
  const int* packed   = (const int*)d_in[1];     // [OUT_F*IN_F/2] int32
  const float* scale  = (const float*)d_in[2];   // [OUT_F,1] fp32
  const float* bias   = (const float*)d_in[3];   // [OUT_F] fp32
  float* out = (float*)d_out;                    // [4,2048,4096] fp32

  signed char* Xq = (signed char*)d_ws;                         // 33.5 MB
  signed char* Wq = Xq + (size_t)M_ROWS * IN_F;                 // 16.8 MB
  float* steps = (float*)(Wq + (size_t)OUT_F * IN_F);           // 32 KB

  k_quant_x<<<M_ROWS, 256, 0, stream>>>(x, Xq, steps);
  k_dequant<<<(OUT_F * IN_F / 2) / (256 * 8), 256, 0, stream>>>(packed, Wq);
  dim3 grid(OUT_F / 128, M_ROWS / 128);
  k_gemm<<<grid, 256, 0, stream>>>(Xq, Wq, steps, scale, bias, out);
}

// Round 3
// 393.185 us; speedup vs baseline: 1.3771x; 1.0562x over previous
//
#include <hip/hip_runtime.h>
#include <stdint.h>

#define IN_F 4096
#define OUT_F 4096
#define M_ROWS 8192

// NF4 codebook pre-scaled to int8: round(c * 127)
__device__ __constant__ int c_nf4_i8[16] = {
    -127, -88, -67, -50, -36, -23, -12, 0, 10, 20, 31, 43, 56, 71, 92, 127};

typedef int i32x4 __attribute__((ext_vector_type(4)));
typedef int i32x16 __attribute__((ext_vector_type(16)));

// ---------------------------------------------------------------------------
// Quantize x per row: one block per row (4096 fp32). Each thread handles 16
// floats (4x float4, coalesced), block-reduces absmax, writes int8 + step.
// ---------------------------------------------------------------------------
__global__ __launch_bounds__(256) void k_quant_x(
    const float* __restrict__ x, signed char* __restrict__ xq,
    float* __restrict__ steps) {
  const int row = blockIdx.x;
  const int tid = threadIdx.x;
  const float4* xr = (const float4*)(x + (size_t)row * IN_F);
  float4 v[4];
  float m = 0.0f;
#pragma unroll
  for (int i = 0; i < 4; ++i) {
    v[i] = xr[tid + 256 * i];
    m = fmaxf(m, fmaxf(fmaxf(fabsf(v[i].x), fabsf(v[i].y)),
                       fmaxf(fabsf(v[i].z), fabsf(v[i].w))));
  }
#pragma unroll
  for (int off = 32; off > 0; off >>= 1) m = fmaxf(m, __shfl_xor(m, off));
  __shared__ float wmax[4];
  if ((tid & 63) == 0) wmax[tid >> 6] = m;
  __syncthreads();
  m = fmaxf(fmaxf(wmax[0], wmax[1]), fmaxf(wmax[2], wmax[3]));
  const float inv = (m > 0.0f) ? 127.0f / m : 0.0f;
  if (tid == 0) steps[row] = m * (1.0f / 127.0f);
  int* oq = (int*)(xq + (size_t)row * IN_F);
#pragma unroll
  for (int i = 0; i < 4; ++i) {
    int q0 = (int)rintf(v[i].x * inv);
    int q1 = (int)rintf(v[i].y * inv);
    int q2 = (int)rintf(v[i].z * inv);
    int q3 = (int)rintf(v[i].w * inv);
    oq[tid + 256 * i] =
        (q0 & 255) | ((q1 & 255) << 8) | ((q2 & 255) << 16) | (q3 << 24);
  }
}

// ---------------------------------------------------------------------------
// Dequantize NF4 -> int8 codebook values (scale folded into GEMM epilogue).
// ---------------------------------------------------------------------------
__global__ __launch_bounds__(256) void k_dequant(
    const int* __restrict__ packed, signed char* __restrict__ W) {
  __shared__ short lut[256];
  {
    const int b = threadIdx.x;
    const int lo = c_nf4_i8[b & 15], hi = c_nf4_i8[b >> 4];
    lut[b] = (short)((lo & 0xFF) | ((hi & 0xFF) << 8));
  }
  __syncthreads();
  const int tid = blockIdx.x * 256 + threadIdx.x;
  const int4 ca = ((const int4*)packed)[2 * tid];
  const int4 cb = ((const int4*)packed)[2 * tid + 1];
  union { short h[8]; int4 v; } o;
  o.h[0] = lut[ca.x]; o.h[1] = lut[ca.y]; o.h[2] = lut[ca.z]; o.h[3] = lut[ca.w];
  o.h[4] = lut[cb.x]; o.h[5] = lut[cb.y]; o.h[6] = lut[cb.z]; o.h[7] = lut[cb.w];
  ((int4*)W)[tid] = o.v;
}

// ---------------------------------------------------------------------------
// int8 GEMM, NT: C = A * B^T. 128x128 block, BK=128, 4 waves 2x2 (64x64),
// mfma_i32_32x32x32_i8 in a 2x2 frag grid, 4 k-steps per iter.
// Bank-conflict-free LDS: rows are 128 B (all 32 banks); 16-B chunk c of row r
// is stored at LDS chunk c ^ (r&7). The swizzle is applied on the GLOBAL
// source side of global_load_lds (LDS dest must stay base + lane*16).
// ---------------------------------------------------------------------------
#define GLL(gptr, lptr)                                          \
  __builtin_amdgcn_global_load_lds(                              \
      (__attribute__((address_space(1))) void*)(gptr),           \
      (__attribute__((address_space(3))) void*)(lptr), 16, 0, 0)

__global__ __launch_bounds__(256) void k_gemm(
    const signed char* __restrict__ A,   // [M_ROWS][IN_F] int8
    const signed char* __restrict__ B,   // [OUT_F][IN_F] int8
    const float* __restrict__ steps,     // [M_ROWS] per-row x step
    const float* __restrict__ scale,     // [OUT_F] per-channel w scale
    const float* __restrict__ bias,      // [OUT_F]
    float* __restrict__ C) {             // [M_ROWS][OUT_F] fp32
  __shared__ __align__(16) signed char sA[128 * 128];
  __shared__ __align__(16) signed char sB[128 * 128];
  const int tid = threadIdx.x;
  const int lane = tid & 63;
  const int w  = tid >> 6;   // wave 0..3
  const int wm = w >> 1;     // 2x2 wave grid, 64x64 per wave
  const int wn = w & 1;
  const int bm = blockIdx.y * 128;
  const int bn = blockIdx.x * 128;

  i32x16 acc[2][2] = {};

  // Staging: per GLL g, wave w, lane l -> LDS row w*32 + g*8 + (l>>3),
  // LDS chunk l&7, which must hold global chunk (l&7) ^ (row&7); row&7 = l>>3.
  const int srow  = w * 32 + (lane >> 3);
  const int schnk = (lane & 7) ^ (lane >> 3);
  const signed char* gA = A + (size_t)(bm + srow) * IN_F + schnk * 16;
  const signed char* gB = B + (size_t)(bn + srow) * IN_F + schnk * 16;
  signed char* lA = sA + w * 32 * 128;  // wave-uniform
  signed char* lB = sB + w * 32 * 128;

  const int r31   = lane & 31;   // m/n within 32-frag
  const int khalf = lane >> 5;   // k half within 32-k-step
  const int rx7   = lane & 7;    // row&7 for de-swizzle

  for (int k0 = 0; k0 < IN_F; k0 += 128) {
#pragma unroll
    for (int g = 0; g < 4; ++g) {
      GLL(gA + k0 + g * 8 * IN_F, lA + g * 1024);
      GLL(gB + k0 + g * 8 * IN_F, lB + g * 1024);
    }
    __syncthreads();
#pragma unroll
    for (int ks = 0; ks < 4; ++ks) {
      const int ch = ((2 * ks + khalf) ^ rx7) * 16;
      i32x4 a0 = *(const i32x4*)&sA[(wm * 64      + r31) * 128 + ch];
      i32x4 a1 = *(const i32x4*)&sA[(wm * 64 + 32 + r31) * 128 + ch];
      i32x4 b0 = *(const i32x4*)&sB[(wn * 64      + r31) * 128 + ch];
      i32x4 b1 = *(const i32x4*)&sB[(wn * 64 + 32 + r31) * 128 + ch];
      acc[0][0] = __builtin_amdgcn_mfma_i32_32x32x32_i8(a0, b0, acc[0][0], 0, 0, 0);
      acc[0][1] = __builtin_amdgcn_mfma_i32_32x32x32_i8(a0, b1, acc[0][1], 0, 0, 0);
      acc[1][0] = __builtin_amdgcn_mfma_i32_32x32x32_i8(a1, b0, acc[1][0], 0, 0, 0);
      acc[1][1] = __builtin_amdgcn_mfma_i32_32x32x32_i8(a1, b1, acc[1][1], 0, 0, 0);
    }
    __syncthreads();
  }

  // Epilogue: 32x32 D layout col = lane&31, row = (reg&3) + 8*(reg>>2) + 4*(lane>>5)
  const int colb = bn + wn * 64 + r31;
  const int rowb = bm + wm * 64 + 4 * khalf;
#pragma unroll
  for (int fj = 0; fj < 2; ++fj) {
    const int col = colb + fj * 32;
    const float fc = scale[col] * (1.0f / 127.0f);
    const float bv = bias[col];
#pragma unroll
    for (int fi = 0; fi < 2; ++fi) {
      const int row0 = rowb + fi * 32;
#pragma unroll
      for (int reg = 0; reg < 16; ++reg) {
        const int row = row0 + (reg & 3) + 8 * (reg >> 2);
        C[(size_t)row * OUT_F + col] =
            (float)acc[fi][fj][reg] * (steps[row] * fc) + bv;
      }
    }
  }
}

extern "C" void kernel_launch(void* const* d_in, const int* in_sizes, int n_in,
                              void* d_out, int out_size, void* d_ws, size_t ws_size,
                              hipStream_t stream) {
  const float* x      = (const float*)d_in[0];   // [4,2048,4096] fp32
  const int* packed   = (const int*)d_in[1];     // [OUT_F*IN_F/2] int32
  const float* scale  = (const float*)d_in[2];   // [OUT_F,1] fp32
  const float* bias   = (const float*)d_in[3];   // [OUT_F] fp32
  float* out = (float*)d_out;                    // [4,2048,4096] fp32

  signed char* Xq = (signed char*)d_ws;                         // 33.5 MB
  signed char* Wq = Xq + (size_t)M_ROWS * IN_F;                 // 16.8 MB
  float* steps = (float*)(Wq + (size_t)OUT_F * IN_F);           // 32 KB

  k_quant_x<<<M_ROWS, 256, 0, stream>>>(x, Xq, steps);
  k_dequant<<<(OUT_F * IN_F / 2) / (256 * 8), 256, 0, stream>>>(packed, Wq);
  dim3 grid(OUT_F / 128, M_ROWS / 128);
  k_gemm<<<grid, 256, 0, stream>>>(Xq, Wq, steps, scale, bias, out);
}